// Round 5
// baseline (158.124 us; speedup 1.0000x reference)
//
#include <hip/hip_runtime.h>
#include <math.h>

// Problem constants: B,H,K,L,V = 4096,1024,10,64,80
constexpr int Bn = 4096;
constexpr int Hn = 1024;
constexpr int Kn = 10;
constexpr int Ln = 64;
constexpr int Vn = 80;
constexpr int NJ = 3 * Kn;   // 30
constexpr int R  = 4;        // batch rows per block
constexpr int NT = 320;      // 5 waves; einsum mapping 4*20*4 = 320, zero idle
constexpr int PJ = 17;       // padded stride for GEMM partials (bank-conflict-free)

// Single fused kernel, grid 1024.
// Key idea: chars panel (80 KB/block) is prefetched into REGISTERS at block
// start (16 float4/thread), before any W load. Plain VGPR loads survive
// __syncthreads (no vmcnt drain) and the in-order vmcnt queue, so the HBM
// stream is in flight during the whole GEMM->exp->phi chain; einsum is then
// memory-free. W loads (issued after chars) drain the queue once per block —
// during that wait HBM is doing useful chars delivery.
__global__ __launch_bounds__(NT) void window_fused(
    const float* __restrict__ x,      // [B,H]
    const float* __restrict__ chars,  // [B,L,V]
    const float* __restrict__ W,      // [H,3K]
    const float* __restrict__ bias,   // [3K]
    float* __restrict__ out)          // [B,V]
{
    __shared__ float4 xs4[R * Hn / 4];   // 16 KB x stage
    __shared__ float  part[R * 512];     // 8 KB GEMM partials, [r][j*17+g]
    __shared__ float  abk[R * NJ];       // 480 B exp(x@W+b)
    __shared__ float  phi_s[R * Ln];     // 1 KB

    const int t    = threadIdx.x;
    const int row0 = blockIdx.x * R;

    // einsum / prefetch mapping: t = rr*80 + v4*4 + q  (quarter of l-range)
    const int q  = t & 3;            // l-quarter: l in [16q, 16q+16)
    const int v4 = (t >> 2) % 20;    // float4 column of V
    const int rr = t / 80;           // batch row within block

    // ---- Phase 0a: x loads FIRST (oldest in vmcnt queue -> LDS-write wait
    //      below is a counted wait that leaves the chars stream in flight).
    float4 xa, xb, xc, xd;
    if (t < 256) {
        const float4* xg4 = (const float4*)(x + (size_t)row0 * Hn); // 16 KB
        xa = xg4[t]; xb = xg4[256 + t]; xc = xg4[512 + t]; xd = xg4[768 + t];
    }
    float bias_v = 0.f;
    if (t < R * NJ) bias_v = bias[t % NJ];   // t<120, consumed much later

    // ---- Phase 0b: chars panel -> registers, fire-and-forget. 16 float4 per
    //      thread = exactly the 5120-float4 panel, no waste, no predication.
    float4 c[16];
    {
        const float4* cb = (const float4*)chars
                         + (size_t)(row0 + rr) * 1280   // row panel (1280 float4)
                         + q * 320 + v4;                // l = 16q.., col v4
#pragma unroll
        for (int i = 0; i < 16; ++i) c[i] = cb[i * 20];
    }

    if (t < 256) {   // x -> LDS (waits only x's 4 loads: counted vmcnt)
        xs4[t] = xa; xs4[256 + t] = xb; xs4[512 + t] = xc; xs4[768 + t] = xd;
    }
    __syncthreads();

    // ---- Phase 1: GEMM partials. jp = j-pair (float2 W loads), g = h-group.
    //      240 active threads; W bytes come from L2 (120 KB, every block).
    {
        const int jp = t & 15;
        const int g  = t >> 4;           // 0..15 for t<256, 64 h each
        if (t < 256 && jp < 15) {
            const float* W2 = W + 2 * jp;
            float aA[R], aB[R];
#pragma unroll
            for (int r0 = 0; r0 < R; ++r0) { aA[r0] = 0.f; aB[r0] = 0.f; }
            const int h0 = g * 64;
#pragma unroll 4
            for (int ii = 0; ii < 64; ii += 4) {
                const int h = h0 + ii;
                float2 w0 = *(const float2*)(W2 + (h + 0) * NJ);
                float2 w1 = *(const float2*)(W2 + (h + 1) * NJ);
                float2 w2 = *(const float2*)(W2 + (h + 2) * NJ);
                float2 w3 = *(const float2*)(W2 + (h + 3) * NJ);
#pragma unroll
                for (int r0 = 0; r0 < R; ++r0) {
                    float4 xv = xs4[r0 * 256 + (h >> 2)];  // LDS broadcast
                    aA[r0] += w0.x * xv.x + w1.x * xv.y + w2.x * xv.z + w3.x * xv.w;
                    aB[r0] += w0.y * xv.x + w1.y * xv.y + w2.y * xv.z + w3.y * xv.w;
                }
            }
#pragma unroll
            for (int r0 = 0; r0 < R; ++r0) {
                part[r0 * 512 + (2 * jp + 0) * PJ + g] = aA[r0];
                part[r0 * 512 + (2 * jp + 1) * PJ + g] = aB[r0];
            }
        }
    }
    __syncthreads();

    // ---- Phase 2: reduce 16 h-groups + bias, exp ----
    if (t < R * NJ) {  // 120 threads
        const int r0 = t / NJ, j = t % NJ;
        float s = bias_v;
#pragma unroll
        for (int gg = 0; gg < 16; ++gg) s += part[r0 * 512 + j * PJ + gg];
        abk[r0 * NJ + j] = __expf(s);
    }
    __syncthreads();

    // ---- Phase 3: phi[r][l] = sum_k alpha*exp(-beta*(kappa-l)^2) ----
    if (t < 256) {
        const int r0 = t >> 6, l = t & 63;
        const float lf = (float)l;
        const float* ab = abk + r0 * NJ;
        float ph = 0.f;
#pragma unroll
        for (int k = 0; k < Kn; ++k) {
            float a  = ab[k];
            float bt = ab[Kn + k];
            float kp = ab[2 * Kn + k];
            float d  = kp - lf;
            ph += a * __expf(-bt * d * d);
        }
        phi_s[r0 * Ln + l] = ph;
    }
    __syncthreads();

    // ---- Phase 4: einsum from registers (chars long since landed) ----
    float4 s = make_float4(0.f, 0.f, 0.f, 0.f);
    const float* ph = phi_s + rr * Ln + q * 16;
#pragma unroll
    for (int i = 0; i < 16; ++i) {
        float p = ph[i];
        s.x += p * c[i].x; s.y += p * c[i].y;
        s.z += p * c[i].z; s.w += p * c[i].w;
    }
    // quarter-reduce: q-groups are 4 adjacent lanes, never straddle a row
    s.x += __shfl_xor(s.x, 1); s.y += __shfl_xor(s.y, 1);
    s.z += __shfl_xor(s.z, 1); s.w += __shfl_xor(s.w, 1);
    s.x += __shfl_xor(s.x, 2); s.y += __shfl_xor(s.y, 2);
    s.z += __shfl_xor(s.z, 2); s.w += __shfl_xor(s.w, 2);

    if (q == 0)
        ((float4*)out)[(size_t)(row0 + rr) * 20 + v4] = s;
}

extern "C" void kernel_launch(void* const* d_in, const int* in_sizes, int n_in,
                              void* d_out, int out_size, void* d_ws, size_t ws_size,
                              hipStream_t stream) {
    const float* x     = (const float*)d_in[0];
    const float* chars = (const float*)d_in[1];
    const float* W     = (const float*)d_in[2];
    const float* bias  = (const float*)d_in[3];
    float* out = (float*)d_out;

    window_fused<<<Bn / R, NT, 0, stream>>>(x, chars, W, bias, out);
}

// Round 6
// 148.630 us; speedup vs baseline: 1.0639x; 1.0639x over previous
//
#include <hip/hip_runtime.h>
#include <math.h>

// Problem constants: B,H,K,L,V = 4096,1024,10,64,80
constexpr int Bn = 4096;
constexpr int Hn = 1024;
constexpr int Kn = 10;
constexpr int Ln = 64;
constexpr int Vn = 80;
constexpr int NJ = 3 * Kn;   // 30
constexpr int R1 = 4;        // rows/block, phi kernel
constexpr int NT1 = 256;

// ---------------------------------------------------------------------------
// K1: phi[b][l] = sum_k alpha*exp(-beta*(kappa-l)^2).  Proven structure
// (passed rounds 1/4). grid 1024, 4 blocks/CU, x-stream + L2-resident W.
// ---------------------------------------------------------------------------
__global__ __launch_bounds__(NT1) void phi_kernel(
    const float* __restrict__ x,      // [B,H]
    const float* __restrict__ W,      // [H,3K]
    const float* __restrict__ bias,   // [3K]
    float* __restrict__ phi)          // [B,L] (workspace)
{
    __shared__ float xs[R1 * Hn];     // 16 KB
    __shared__ float part[R1 * 256];  // 4 KB
    __shared__ float abk[R1 * NJ];    // 480 B

    const int t    = threadIdx.x;
    const int row0 = blockIdx.x * R1;

    const float4* x4  = (const float4*)x;
    float4*       xs4 = (float4*)xs;
#pragma unroll
    for (int r = 0; r < R1; ++r)
        xs4[r * (Hn / 4) + t] = x4[(size_t)(row0 + r) * (Hn / 4) + t];
    __syncthreads();

    // GEMM partials: j = t&31 (j<30 active), g = t>>5 covers 128 h each.
    // W loads are coalesced across j-lanes (consecutive floats).
    const int j = t & 31;
    const int g = t >> 5;
    float acc0 = 0.f, acc1 = 0.f, acc2 = 0.f, acc3 = 0.f;
    if (j < NJ) {
        const float* Wp = W + j;
        const int h0 = g * 128;
#pragma unroll 4
        for (int ii = 0; ii < 128; ii += 4) {
            const int h  = h0 + ii;
            const int h4 = h >> 2;
            float4 xa = xs4[0 * (Hn / 4) + h4];   // LDS broadcast across j
            float4 xb = xs4[1 * (Hn / 4) + h4];
            float4 xc = xs4[2 * (Hn / 4) + h4];
            float4 xd = xs4[3 * (Hn / 4) + h4];
            float w0 = Wp[(h + 0) * NJ];
            float w1 = Wp[(h + 1) * NJ];
            float w2 = Wp[(h + 2) * NJ];
            float w3 = Wp[(h + 3) * NJ];
            acc0 += w0 * xa.x + w1 * xa.y + w2 * xa.z + w3 * xa.w;
            acc1 += w0 * xb.x + w1 * xb.y + w2 * xb.z + w3 * xb.w;
            acc2 += w0 * xc.x + w1 * xc.y + w2 * xc.z + w3 * xc.w;
            acc3 += w0 * xd.x + w1 * xd.y + w2 * xd.z + w3 * xd.w;
        }
    }
    part[0 * 256 + g * 32 + j] = acc0;
    part[1 * 256 + g * 32 + j] = acc1;
    part[2 * 256 + g * 32 + j] = acc2;
    part[3 * 256 + g * 32 + j] = acc3;
    __syncthreads();

    if (t < R1 * NJ) {  // 120 threads
        const int r = t / NJ, jj = t % NJ;
        float s = bias[jj];
#pragma unroll
        for (int gg = 0; gg < 8; ++gg) s += part[r * 256 + gg * 32 + jj];
        abk[r * NJ + jj] = __expf(s);
    }
    __syncthreads();

    // phi: 256 threads -> 256 consecutive floats (coalesced)
    {
        const int r = t >> 6, l = t & 63;
        const float lf = (float)l;
        const float* ab = abk + r * NJ;
        float ph = 0.f;
#pragma unroll
        for (int k = 0; k < Kn; ++k) {
            float a  = ab[k];
            float bt = ab[Kn + k];
            float kp = ab[2 * Kn + k];
            float d  = kp - lf;
            ph += a * __expf(-bt * d * d);
        }
        phi[(size_t)row0 * Ln + t] = ph;
    }
}

// ---------------------------------------------------------------------------
// K2: out[b][v] = sum_l phi[b][l] * chars[b][l][v].
// ONE WAVE PER ROW, 64-thread blocks, grid 4096 -> 16 INDEPENDENT waves/CU,
// no inter-wave barriers, no shared staging of zero-reuse data.
// Lane map: ll=(lane<60?lane:lane-60); ls=ll/20 (l-subset, stride 3);
// v4=ll%20 (float4 column). Lanes 60-63 duplicate lanes 0-3 (values defined
// for shuffles, never consumed). Consecutive lanes read consecutive float4s:
// one instruction covers ~960 B contiguous.
// ---------------------------------------------------------------------------
__global__ __launch_bounds__(64) void einsum_kernel(
    const float* __restrict__ phi,    // [B,L]
    const float* __restrict__ chars,  // [B,L,V]
    float* __restrict__ out)          // [B,V]
{
    __shared__ float ph[Ln];          // 256 B

    const int lane = threadIdx.x;     // 0..63
    const int row  = blockIdx.x;

    ph[lane] = phi[(size_t)row * Ln + lane];   // one coalesced 64-lane load
    __syncthreads();

    const int ll = (lane < 60) ? lane : lane - 60;
    const int ls = ll / 20;           // 0..2  (l covers ls, ls+3, ls+6, ...)
    const int v4 = ll % 20;           // float4 column

    const float4* cb = (const float4*)chars + (size_t)row * (Ln * Vn / 4);

    float4 acc = make_float4(0.f, 0.f, 0.f, 0.f);
#pragma unroll
    for (int i = 0; i < 22; ++i) {    // 22 independent float4 loads (ls=0), 21 else
        const int l = ls + 3 * i;
        if (l < Ln) {
            float4 c = cb[l * (Vn / 4) + v4];
            float  p = ph[l];         // LDS broadcast (3 distinct addrs/wave)
            acc.x += p * c.x; acc.y += p * c.y;
            acc.z += p * c.z; acc.w += p * c.w;
        }
    }

    // reduce the 3 l-subsets: lanes 0-19 pull from lanes +20 and +40
    acc.x += __shfl(acc.x, lane + 20) + __shfl(acc.x, lane + 40);
    acc.y += __shfl(acc.y, lane + 20) + __shfl(acc.y, lane + 40);
    acc.z += __shfl(acc.z, lane + 20) + __shfl(acc.z, lane + 40);
    acc.w += __shfl(acc.w, lane + 20) + __shfl(acc.w, lane + 40);

    if (lane < 20)
        ((float4*)out)[(size_t)row * (Vn / 4) + lane] = acc;  // 320 B coalesced
}

// ---------------------------------------------------------------------------
// Fused fallback — only if ws too small (proven round-0 kernel).
// ---------------------------------------------------------------------------
__global__ __launch_bounds__(NT1) void window_kernel(
    const float* __restrict__ x,
    const float* __restrict__ chars,
    const float* __restrict__ W,
    const float* __restrict__ bias,
    float* __restrict__ out)
{
    __shared__ float  xs[R1 * Hn];
    __shared__ float  part[R1 * 256];
    __shared__ float  abk[R1 * NJ];
    __shared__ float  phi_s[R1 * Ln];
    __shared__ float4 cpart[R1 * 12 * 20];

    const int t    = threadIdx.x;
    const int row0 = blockIdx.x * R1;

    const float4* x4  = (const float4*)x;
    float4*       xs4 = (float4*)xs;
#pragma unroll
    for (int r = 0; r < R1; ++r)
        xs4[r * (Hn / 4) + t] = x4[(size_t)(row0 + r) * (Hn / 4) + t];
    __syncthreads();

    const int j = t & 31;
    const int g = t >> 5;
    float acc0 = 0.f, acc1 = 0.f, acc2 = 0.f, acc3 = 0.f;
    if (j < NJ) {
        const float* Wp = W + j;
        const int h0 = g * 128;
#pragma unroll 4
        for (int ii = 0; ii < 128; ii += 4) {
            const int h  = h0 + ii;
            const int h4 = h >> 2;
            float4 xa = xs4[0 * (Hn / 4) + h4];
            float4 xb = xs4[1 * (Hn / 4) + h4];
            float4 xc = xs4[2 * (Hn / 4) + h4];
            float4 xd = xs4[3 * (Hn / 4) + h4];
            float w0 = Wp[(h + 0) * NJ];
            float w1 = Wp[(h + 1) * NJ];
            float w2 = Wp[(h + 2) * NJ];
            float w3 = Wp[(h + 3) * NJ];
            acc0 += w0 * xa.x + w1 * xa.y + w2 * xa.z + w3 * xa.w;
            acc1 += w0 * xb.x + w1 * xb.y + w2 * xb.z + w3 * xb.w;
            acc2 += w0 * xc.x + w1 * xc.y + w2 * xc.z + w3 * xc.w;
            acc3 += w0 * xd.x + w1 * xd.y + w2 * xd.z + w3 * xd.w;
        }
    }
    part[0 * 256 + g * 32 + j] = acc0;
    part[1 * 256 + g * 32 + j] = acc1;
    part[2 * 256 + g * 32 + j] = acc2;
    part[3 * 256 + g * 32 + j] = acc3;
    __syncthreads();

    if (t < R1 * NJ) {
        const int r = t / NJ, jj = t % NJ;
        float s = bias[jj];
#pragma unroll
        for (int gg = 0; gg < 8; ++gg) s += part[r * 256 + gg * 32 + jj];
        abk[r * NJ + jj] = __expf(s);
    }
    __syncthreads();

    {
        const int r = t >> 6, l = t & 63;
        const float lf = (float)l;
        const float* ab = abk + r * NJ;
        float ph = 0.f;
#pragma unroll
        for (int k = 0; k < Kn; ++k) {
            float a  = ab[k];
            float bt = ab[Kn + k];
            float kp = ab[2 * Kn + k];
            float d  = kp - lf;
            ph += a * __expf(-bt * d * d);
        }
        phi_s[r * Ln + l] = ph;
    }
    __syncthreads();

    const float4* c4 = (const float4*)chars;
    if (t < 240) {
        const int v4  = t % 20;
        const int g12 = t / 20;
        float4 s0 = make_float4(0.f, 0.f, 0.f, 0.f);
        float4 s1 = s0, s2 = s0, s3 = s0;
        for (int l = g12; l < Ln; l += 12) {
            const int off = l * 20 + v4;
            float4 cA = c4[(size_t)(row0 + 0) * 1280 + off];
            float4 cB = c4[(size_t)(row0 + 1) * 1280 + off];
            float4 cC = c4[(size_t)(row0 + 2) * 1280 + off];
            float4 cD = c4[(size_t)(row0 + 3) * 1280 + off];
            float p0 = phi_s[0 * Ln + l];
            float p1 = phi_s[1 * Ln + l];
            float p2 = phi_s[2 * Ln + l];
            float p3 = phi_s[3 * Ln + l];
            s0.x += p0 * cA.x; s0.y += p0 * cA.y; s0.z += p0 * cA.z; s0.w += p0 * cA.w;
            s1.x += p1 * cB.x; s1.y += p1 * cB.y; s1.z += p1 * cB.z; s1.w += p1 * cB.w;
            s2.x += p2 * cC.x; s2.y += p2 * cC.y; s2.z += p2 * cC.z; s2.w += p2 * cC.w;
            s3.x += p3 * cD.x; s3.y += p3 * cD.y; s3.z += p3 * cD.z; s3.w += p3 * cD.w;
        }
        cpart[(0 * 12 + g12) * 20 + v4] = s0;
        cpart[(1 * 12 + g12) * 20 + v4] = s1;
        cpart[(2 * 12 + g12) * 20 + v4] = s2;
        cpart[(3 * 12 + g12) * 20 + v4] = s3;
    }
    __syncthreads();

    if (t < 80) {
        const int r  = t / 20;
        const int vv = t % 20;
        float4 s = make_float4(0.f, 0.f, 0.f, 0.f);
#pragma unroll
        for (int gg = 0; gg < 12; ++gg) {
            float4 p = cpart[(r * 12 + gg) * 20 + vv];
            s.x += p.x; s.y += p.y; s.z += p.z; s.w += p.w;
        }
        ((float4*)out)[(size_t)(row0 + r) * 20 + vv] = s;
    }
}

extern "C" void kernel_launch(void* const* d_in, const int* in_sizes, int n_in,
                              void* d_out, int out_size, void* d_ws, size_t ws_size,
                              hipStream_t stream) {
    const float* x     = (const float*)d_in[0];
    const float* chars = (const float*)d_in[1];
    const float* W     = (const float*)d_in[2];
    const float* bias  = (const float*)d_in[3];
    float* out = (float*)d_out;

    const size_t phi_bytes = (size_t)Bn * Ln * sizeof(float);  // 1 MB
    if (d_ws != nullptr && ws_size >= phi_bytes) {
        float* phi = (float*)d_ws;
        phi_kernel<<<Bn / R1, NT1, 0, stream>>>(x, W, bias, phi);
        einsum_kernel<<<Bn, 64, 0, stream>>>(phi, chars, out);
    } else {
        window_kernel<<<Bn / R1, NT1, 0, stream>>>(x, chars, W, bias, out);
    }
}